// Round 7
// baseline (3155.555 us; speedup 1.0000x reference)
//
#include <hip/hip_runtime.h>

#define TT   8192
#define DDIM 2048
#define HDIM 7168
#define NEXP 8
#define MT   32                 // max M-tiles per expert (8192/256)
#define NT1  (HDIM / 128)       // 56 n-tiles for gemm1 (128 h1 + 128 h3 cols each)
#define NT2  (DDIM / 256)       // 8 n-tiles for gemm2

typedef __attribute__((ext_vector_type(8))) short bf16x8;
typedef __attribute__((ext_vector_type(4))) short short4v;
typedef __attribute__((ext_vector_type(4))) float f32x4;
typedef const __attribute__((address_space(3))) char* lds_ptr;

__device__ __forceinline__ unsigned short f2bf(float f) {
  unsigned int u = __builtin_bit_cast(unsigned int, f);
  u += 0x7fffu + ((u >> 16) & 1u);   // RNE
  return (unsigned short)(u >> 16);
}

__device__ __forceinline__ void gload_lds16(const void* gp, void* lp) {
  __builtin_amdgcn_global_load_lds((__attribute__((address_space(1))) void*)gp,
                                   (__attribute__((address_space(3))) void*)lp,
                                   16, 0, 0);
}

__device__ __forceinline__ void mfma16(f32x4& c, bf16x8 a, bf16x8 b) {
  c = __builtin_amdgcn_mfma_f32_16x16x32_bf16(a, b, c, 0, 0, 0);
}

// asm ds_read: keeps lgkm counting authoritative (no compiler-inserted
// lgkmcnt(0) before the MFMA that would drain the pipelined reads).
__device__ __forceinline__ bf16x8 ds_read128(lds_ptr p) {
  bf16x8 r;
  asm volatile("ds_read_b128 %0, %1" : "=&v"(r) : "v"(p));
  return r;
}

__device__ __forceinline__ void wg_barrier() {
  asm volatile("" ::: "memory");
  __builtin_amdgcn_s_barrier();
  asm volatile("" ::: "memory");
}

// ---- 8-phase schedule, ds_reads pipelined one phase ahead ----
// LDS per buffer (64KB): A_k0 | A_k1 | B_k0 | B_k1, each [256 rows][32 k] bf16
// (row stride 64B, XOR-swizzled 16B chunks). buf0 @0, buf1 @65536.
// Phase p: [asm ds_reads for phase p+1 into alternate reg set][stage per
// r5-validated ledger][barrier][lgkmcnt(4/8): retires p-1's reads (= this
// phase's operands), keeps p's in flight][sched_barrier][MFMA][vmcnt(8)]
// [barrier].  Ledger invariants (hand-verified): restage s = last-read-issue
// r + 2 for every region; stage->read-issue distance 5-6 phases and
// vmcnt(8)-every-phase guarantees stages <= p-5 landed before reads at p-top.
#define PH2(HH, AF, BF, NBA, AFN, NBB, BFN, STG, SRCP, SOFF, LGK, VM)        \
  do {                                                                       \
    if ((NBA) >= 0) {                                                        \
      _Pragma("unroll")                                                      \
      for (int m = 0; m < 4; ++m)                                            \
        AFN[m] = ds_read128(lds3 + (NBA) + rA + m * 1024);                   \
    }                                                                        \
    if ((NBB) >= 0) {                                                        \
      _Pragma("unroll")                                                      \
      for (int n = 0; n < 4; ++n)                                            \
        BFN[n] = ds_read128(lds3 + (NBB) + rB + n * 1024);                   \
    }                                                                        \
    if ((STG) >= 0) {                                                        \
      gload_lds16(SRCP[0] + (SOFF), smem + (STG) + wid * 2048);              \
      gload_lds16(SRCP[1] + (SOFF), smem + (STG) + wid * 2048 + 1024);       \
    }                                                                        \
    wg_barrier();                                                            \
    if ((LGK) == 8) asm volatile("s_waitcnt lgkmcnt(8)" ::: "memory");       \
    if ((LGK) == 4) asm volatile("s_waitcnt lgkmcnt(4)" ::: "memory");       \
    if ((LGK) == 0) asm volatile("s_waitcnt lgkmcnt(0)" ::: "memory");       \
    __builtin_amdgcn_sched_barrier(0);                                       \
    __builtin_amdgcn_s_setprio(1);                                           \
    _Pragma("unroll")                                                        \
    for (int n = 0; n < 4; ++n) {                                            \
      _Pragma("unroll")                                                      \
      for (int m = 0; m < 4; ++m)                                            \
        mfma16(acc[(HH) + m][n], AF[m], BF[n]);                              \
    }                                                                        \
    __builtin_amdgcn_s_setprio(0);                                           \
    __builtin_amdgcn_sched_barrier(0);                                       \
    if ((VM) == 8) asm volatile("s_waitcnt vmcnt(8)" ::: "memory");          \
    if ((VM) == 0) asm volatile("s_waitcnt vmcnt(0)" ::: "memory");          \
    wg_barrier();                                                            \
  } while (0)

// MFMA region schedule (r5-validated): p1/2: buf0 A_k0+B_k0; p3/4: A_k1+B_k1;
// p5/6: buf1 A_k0+B_k0; p7/8: A_k1+B_k1.  Loads in p fetch p+1's fragments.
// Reg sets: MFMA af alternates af1(odd)/af0(even); bf0 for p1/2,p5/6, bf1 for
// p3/4,p7/8; loads write the set not in use.
#define ITER_FULL2(kb)                                                         \
  PH2(0, af1, bf0, 4096,  af0, -1,     bf1, 81920,  asrc, (kb) + 192, 4, 8);   \
  PH2(4, af0, bf0, 16384, af1, 49152,  bf1, 32768,  bsrc, (kb) + 256, 8, 8);   \
  PH2(0, af1, bf1, 20480, af0, -1,     bf0, 0,      asrc, (kb) + 256, 4, 8);   \
  PH2(4, af0, bf1, 65536, af1, 98304,  bf0, 49152,  bsrc, (kb) + 320, 8, 8);   \
  PH2(0, af1, bf0, 69632, af0, -1,     bf1, 16384,  asrc, (kb) + 320, 4, 8);   \
  PH2(4, af0, bf0, 81920, af1, 114688, bf1, 98304,  bsrc, (kb) + 384, 8, 8);   \
  PH2(0, af1, bf1, 86016, af0, -1,     bf0, 65536,  asrc, (kb) + 384, 4, 8);   \
  PH2(4, af0, bf1, 0,     af1, 32768,  bf0, 114688, bsrc, (kb) + 448, 8, 8);

// Last iteration: only p1 stages; vmcnt(0) at p4 drains; p8 loads nothing.
#define ITER_LAST2(kb)                                                         \
  PH2(0, af1, bf0, 4096,  af0, -1,     bf1, 81920, asrc, (kb) + 192, 4, 8);    \
  PH2(4, af0, bf0, 16384, af1, 49152,  bf1, -1,    asrc, 0,          8, 8);    \
  PH2(0, af1, bf1, 20480, af0, -1,     bf0, -1,    asrc, 0,          4, 8);    \
  PH2(4, af0, bf1, 65536, af1, 98304,  bf0, -1,    asrc, 0,          8, 0);    \
  PH2(0, af1, bf0, 69632, af0, -1,     bf1, -1,    asrc, 0,          4, 8);    \
  PH2(4, af0, bf0, 81920, af1, 114688, bf1, -1,    asrc, 0,          8, 8);    \
  PH2(0, af1, bf1, 86016, af0, -1,     bf0, -1,    asrc, 0,          4, 8);    \
  PH2(4, af0, bf1, -1,    af1, -1,     bf0, -1,    asrc, 0,          0, 8);

// Prologue staging: unchanged from r5/r6 (validated); then preload phase-1
// fragments (regions staged+published by the vmcnt(6)+barrier).
#define PROLOGUE()                                                           \
  do {                                                                       \
    gload_lds16(asrc[0] + 0,   smem + 0      + wid * 2048);                  \
    gload_lds16(asrc[1] + 0,   smem + 0      + wid * 2048 + 1024);           \
    gload_lds16(bsrc[0] + 0,   smem + 32768  + wid * 2048);                  \
    gload_lds16(bsrc[1] + 0,   smem + 32768  + wid * 2048 + 1024);           \
    gload_lds16(asrc[0] + 64,  smem + 16384  + wid * 2048);                  \
    gload_lds16(asrc[1] + 64,  smem + 16384  + wid * 2048 + 1024);           \
    gload_lds16(bsrc[0] + 64,  smem + 49152  + wid * 2048);                  \
    gload_lds16(bsrc[1] + 64,  smem + 49152  + wid * 2048 + 1024);           \
    gload_lds16(bsrc[0] + 128, smem + 98304  + wid * 2048);                  \
    gload_lds16(bsrc[1] + 128, smem + 98304  + wid * 2048 + 1024);           \
    gload_lds16(asrc[0] + 128, smem + 65536  + wid * 2048);                  \
    gload_lds16(asrc[1] + 128, smem + 65536  + wid * 2048 + 1024);           \
    gload_lds16(bsrc[0] + 192, smem + 114688 + wid * 2048);                  \
    gload_lds16(bsrc[1] + 192, smem + 114688 + wid * 2048 + 1024);           \
    asm volatile("s_waitcnt vmcnt(6)" ::: "memory");                         \
    wg_barrier();                                                            \
    _Pragma("unroll")                                                        \
    for (int m = 0; m < 4; ++m)                                              \
      af1[m] = ds_read128(lds3 + 0 + rA + m * 1024);                         \
    _Pragma("unroll")                                                        \
    for (int n = 0; n < 4; ++n)                                              \
      bf0[n] = ds_read128(lds3 + 32768 + rB + n * 1024);                     \
  } while (0)

// ---------------- fp32 -> bf16 elementwise ----------------
__global__ __launch_bounds__(256) void cvt_bf16_kernel(const float* __restrict__ src,
                                                       unsigned short* __restrict__ dst,
                                                       long n4) {
  long i = (long)blockIdx.x * 256 + threadIdx.x;
  long stride = (long)gridDim.x * 256;
  for (; i < n4; i += stride) {
    float4 v = ((const float4*)src)[i];
    short4v s;
    s[0] = (short)f2bf(v.x); s[1] = (short)f2bf(v.y);
    s[2] = (short)f2bf(v.z); s[3] = (short)f2bf(v.w);
    ((short4v*)dst)[i] = s;
  }
}

// ---------------- gate ----------------
__global__ __launch_bounds__(256) void gate_kernel(const float* __restrict__ x,
                                                   const float* __restrict__ gw,
                                                   int* __restrict__ route_e,
                                                   float* __restrict__ route_w,
                                                   int* __restrict__ counts) {
  int t = blockIdx.x;
  int tid = threadIdx.x;
  const float* xr = x + (size_t)t * DDIM;
  float p[NEXP];
#pragma unroll
  for (int e = 0; e < NEXP; ++e) p[e] = 0.f;
#pragma unroll
  for (int c = 0; c < DDIM / (256 * 4); ++c) {
    int d = (c * 256 + tid) * 4;
    float4 xv = *(const float4*)(xr + d);
#pragma unroll
    for (int e = 0; e < NEXP; ++e) {
      float4 wv = *(const float4*)(gw + (size_t)e * DDIM + d);
      p[e] += xv.x * wv.x + xv.y * wv.y + xv.z * wv.z + xv.w * wv.w;
    }
  }
  __shared__ float red[NEXP][4];
  int lane = tid & 63, wid = tid >> 6;
#pragma unroll
  for (int e = 0; e < NEXP; ++e) {
    float v = p[e];
    for (int o = 32; o > 0; o >>= 1) v += __shfl_down(v, o);
    if (lane == 0) red[e][wid] = v;
  }
  __syncthreads();
  if (tid == 0) {
    float lg[NEXP];
#pragma unroll
    for (int e = 0; e < NEXP; ++e) lg[e] = red[e][0] + red[e][1] + red[e][2] + red[e][3];
    int i0 = 0;
#pragma unroll
    for (int e = 1; e < NEXP; ++e) if (lg[e] > lg[i0]) i0 = e;
    int i1 = -1;
#pragma unroll
    for (int e = 0; e < NEXP; ++e) {
      if (e == i0) continue;
      if (i1 < 0 || lg[e] > lg[i1]) i1 = e;
    }
    float w0 = 1.f / (1.f + __expf(lg[i1] - lg[i0]));
    float w1 = 1.f - w0;
    route_e[t * 2 + 0] = i0;  route_e[t * 2 + 1] = i1;
    route_w[t * 2 + 0] = w0;  route_w[t * 2 + 1] = w1;
    atomicAdd(&counts[i0], 1);
    atomicAdd(&counts[i1], 1);
  }
}

__global__ void scan_kernel(const int* __restrict__ counts, int* __restrict__ offsets,
                            int* __restrict__ cursor) {
  if (threadIdx.x == 0 && blockIdx.x == 0) {
    int o = 0;
    for (int e = 0; e < NEXP; ++e) { offsets[e] = o; cursor[e] = o; o += counts[e]; }
  }
}

__global__ __launch_bounds__(256) void scatter_kernel(const int* __restrict__ route_e,
                                                      const float* __restrict__ route_w,
                                                      int* __restrict__ cursor,
                                                      int* __restrict__ tok_list,
                                                      float* __restrict__ tok_w) {
  int t = blockIdx.x * 256 + threadIdx.x;
  if (t >= TT) return;
#pragma unroll
  for (int s = 0; s < 2; ++s) {
    int e = route_e[t * 2 + s];
    int p = atomicAdd(&cursor[e], 1);
    tok_list[p] = t;
    tok_w[p] = route_w[t * 2 + s];
  }
}

// ---------------- w2 [H,D] fp32 -> w2t [D,H] bf16 ----------------
__global__ __launch_bounds__(256) void transpose_w2_kernel(const float* __restrict__ w2,
                                                           unsigned short* __restrict__ w2t,
                                                           int expert_fixed) {
  int e = expert_fixed >= 0 ? expert_fixed : (int)blockIdx.z;
  const float* src = w2 + (size_t)e * HDIM * DDIM;
  unsigned short* dst = w2t + (expert_fixed >= 0 ? (size_t)0 : (size_t)e * DDIM * HDIM);
  int h0 = blockIdx.x * 64, d0 = blockIdx.y * 64;
  __shared__ __align__(8) unsigned short tile[64 * 66];
  int tid = threadIdx.x;
  int hr = tid >> 2;
#pragma unroll
  for (int j = 0; j < 4; ++j) {
    int f4 = (tid & 3) + j * 4;
    float4 v = *(const float4*)(src + (size_t)(h0 + hr) * DDIM + d0 + f4 * 4);
    unsigned int lo = (unsigned int)f2bf(v.x) | ((unsigned int)f2bf(v.y) << 16);
    unsigned int hi = (unsigned int)f2bf(v.z) | ((unsigned int)f2bf(v.w) << 16);
    char* bp = (char*)tile + hr * 132 + f4 * 8;
    *(unsigned int*)bp = lo;
    *(unsigned int*)(bp + 4) = hi;
  }
  __syncthreads();
  int dr = tid >> 2;
  int hbase = (tid & 3) * 16;
  unsigned short vals[16];
#pragma unroll
  for (int i = 0; i < 16; ++i)
    vals[i] = *(unsigned short*)((char*)tile + (hbase + i) * 132 + dr * 2);
  unsigned short* op = dst + (size_t)(d0 + dr) * HDIM + h0 + hbase;
#pragma unroll
  for (int j = 0; j < 4; ++j) {
    short4v s;
    s[0] = (short)vals[j * 4 + 0]; s[1] = (short)vals[j * 4 + 1];
    s[2] = (short)vals[j * 4 + 2]; s[3] = (short)vals[j * 4 + 3];
    *(short4v*)(op + j * 4) = s;
  }
}

// =====================================================================
// GEMM1: g = silu(Xe w1^T) * (Xe w3^T); 256x256 tile (128 w1 + 128 w3
// cols), BK=64, 8 waves, pipelined-reads 8-phase schedule.
// =====================================================================
__global__ __launch_bounds__(512, 2) void gemm1_kernel(
    const unsigned short* __restrict__ xbf, const unsigned short* __restrict__ w1b,
    const unsigned short* __restrict__ w3b, const int* __restrict__ tok_list,
    const int* __restrict__ counts, const int* __restrict__ offsets,
    unsigned short* __restrict__ g, int expert_fixed) {
  __shared__ __align__(16) char smem[133120];   // 128KB staging + epi hb[256][130] f32
  constexpr int NI = DDIM / 128;                // 16 iterations (2 K-tiles each)

  int nwg = gridDim.x;
  int orig = blockIdx.x;
  int wg = (orig & 7) * (nwg >> 3) + (orig >> 3);   // bijective XCD swizzle (nwg%8==0)
  int mt = wg & (MT - 1);
  int rem = wg >> 5;
  int nt = rem % NT1;
  int e = expert_fixed >= 0 ? expert_fixed : rem / NT1;

  int cnt = counts[e];
  int mbase = mt * 256;
  if (mbase >= cnt) return;
  int off = offsets[e];
  int gshift = expert_fixed >= 0 ? 0 : off;
  int rows = cnt - mbase; if (rows > 256) rows = 256;

  const unsigned short* w1e = expert_fixed >= 0 ? w1b : w1b + (size_t)e * HDIM * DDIM;
  const unsigned short* w3e = expert_fixed >= 0 ? w3b : w3b + (size_t)e * HDIM * DDIM;

  int tid = threadIdx.x, lane = tid & 63, wid = tid >> 6;
  int wr = wid >> 2, wc = wid & 3;
  lds_ptr lds3 = (lds_ptr)smem;

  // staging sources: per half-tile gload j, wave covers rows wid*32+j*16+(lane>>2)
  int r16 = lane >> 2;
  int csrc = (lane & 3) ^ ((lane >> 3) & 3);    // pre-swizzled source chunk
  const char* asrc[2]; const char* bsrc[2];
#pragma unroll
  for (int j = 0; j < 2; ++j) {
    int r = wid * 32 + j * 16 + r16;
    int m = mbase + r; if (m > cnt - 1) m = cnt - 1;
    int tok = tok_list[off + m];
    asrc[j] = (const char*)xbf + (size_t)tok * (DDIM * 2) + csrc * 16;
    const char* base = (r < 128)
        ? (const char*)w1e + (size_t)(nt * 128 + r) * (DDIM * 2)
        : (const char*)w3e + (size_t)(nt * 128 + r - 128) * (DDIM * 2);
    bsrc[j] = base + csrc * 16;
  }
  // fragment read offsets (lane-constant)
  int rA = (wr * 128 + (lane & 15)) * 64 + (((lane >> 4) ^ ((lane >> 1) & 3)) * 16);
  int rB = (wc * 64  + (lane & 15)) * 64 + (((lane >> 4) ^ ((lane >> 1) & 3)) * 16);

  f32x4 zv = {0.f, 0.f, 0.f, 0.f};
  f32x4 acc[8][4];
#pragma unroll
  for (int m = 0; m < 8; ++m)
#pragma unroll
    for (int n = 0; n < 4; ++n) acc[m][n] = zv;
  bf16x8 af0[4], af1[4], bf0[4], bf1[4];

  PROLOGUE();
#pragma unroll 1
  for (int i = 0; i < NI - 1; ++i) {
    size_t kb = (size_t)i * 256;
    ITER_FULL2(kb);
  }
  {
    size_t kb = (size_t)(NI - 1) * 256;
    ITER_LAST2(kb);
  }

  // ---- epilogue: h1 (wc<2) -> LDS; h3 (wc>=2) computes g = silu(h1)*h3 ----
  float* hb = (float*)smem;                       // [256][130] f32
  if (wc < 2) {
#pragma unroll
    for (int m = 0; m < 8; ++m)
#pragma unroll
      for (int q = 0; q < 4; ++q) {
        int row = wr * 128 + m * 16 + (lane >> 4) * 4 + q;
        int col = wc * 64 + (lane & 15);
#pragma unroll
        for (int n = 0; n < 4; ++n)
          hb[row * 130 + col + n * 16] = acc[m][n][q];
      }
  }
  asm volatile("s_waitcnt lgkmcnt(0)" ::: "memory");
  wg_barrier();
  if (wc >= 2) {
#pragma unroll
    for (int m = 0; m < 8; ++m)
#pragma unroll
      for (int q = 0; q < 4; ++q) {
        int row = wr * 128 + m * 16 + (lane >> 4) * 4 + q;
        if (row >= rows) continue;
        size_t grow = (size_t)(mbase + row + gshift);
        int colbase = (wc - 2) * 64 + (lane & 15);
        unsigned short* gp = g + grow * HDIM + nt * 128 + colbase;
#pragma unroll
        for (int n = 0; n < 4; ++n) {
          float h1 = hb[row * 130 + colbase + n * 16];
          float h3 = acc[m][n][q];
          float gv = (h1 / (1.f + __expf(-h1))) * h3;
          gp[n * 16] = f2bf(gv);
        }
      }
  }
}

// =====================================================================
// GEMM2: out += wt * (g @ w2) via w2t, same schedule, atomic epilogue.
// =====================================================================
__global__ __launch_bounds__(512, 2) void gemm2_kernel(
    const unsigned short* __restrict__ g, const unsigned short* __restrict__ w2t,
    const int* __restrict__ tok_list, const float* __restrict__ tok_w,
    const int* __restrict__ counts, const int* __restrict__ offsets,
    float* __restrict__ out, int expert_fixed) {
  __shared__ __align__(16) char smem[131072];
  constexpr int NI = HDIM / 128;                // 56 iterations

  int nwg = gridDim.x;
  int orig = blockIdx.x;
  int wg = (orig & 7) * (nwg >> 3) + (orig >> 3);
  int mt = wg & (MT - 1);
  int rem = wg >> 5;
  int nt = rem % NT2;
  int e = expert_fixed >= 0 ? expert_fixed : rem / NT2;

  int cnt = counts[e];
  int mbase = mt * 256;
  if (mbase >= cnt) return;
  int off = offsets[e];
  int gshift = expert_fixed >= 0 ? 0 : off;
  int nbase = nt * 256;
  int rows = cnt - mbase; if (rows > 256) rows = 256;
  const unsigned short* w2te = w2t + (expert_fixed >= 0 ? (size_t)0 : (size_t)e * DDIM * HDIM);

  int tid = threadIdx.x, lane = tid & 63, wid = tid >> 6;
  int wr = wid >> 2, wc = wid & 3;
  lds_ptr lds3 = (lds_ptr)smem;

  int r16 = lane >> 2;
  int csrc = (lane & 3) ^ ((lane >> 3) & 3);
  const char* asrc[2]; const char* bsrc[2];
#pragma unroll
  for (int j = 0; j < 2; ++j) {
    int r = wid * 32 + j * 16 + r16;
    int m = mbase + r; if (m > cnt - 1) m = cnt - 1;
    asrc[j] = (const char*)g + (size_t)(m + gshift) * (HDIM * 2) + csrc * 16;
    bsrc[j] = (const char*)w2te + (size_t)(nbase + r) * (HDIM * 2) + csrc * 16;
  }
  int rA = (wr * 128 + (lane & 15)) * 64 + (((lane >> 4) ^ ((lane >> 1) & 3)) * 16);
  int rB = (wc * 64  + (lane & 15)) * 64 + (((lane >> 4) ^ ((lane >> 1) & 3)) * 16);

  f32x4 zv = {0.f, 0.f, 0.f, 0.f};
  f32x4 acc[8][4];
#pragma unroll
  for (int m = 0; m < 8; ++m)
#pragma unroll
    for (int n = 0; n < 4; ++n) acc[m][n] = zv;
  bf16x8 af0[4], af1[4], bf0[4], bf1[4];

  PROLOGUE();
#pragma unroll 1
  for (int i = 0; i < NI - 1; ++i) {
    size_t kb = (size_t)i * 256;
    ITER_FULL2(kb);
  }
  {
    size_t kb = (size_t)(NI - 1) * 256;
    ITER_LAST2(kb);
  }

#pragma unroll
  for (int m = 0; m < 8; ++m)
#pragma unroll
    for (int q = 0; q < 4; ++q) {
      int row = wr * 128 + m * 16 + (lane >> 4) * 4 + q;
      if (row >= rows) continue;
      int mi = mbase + row;
      int tok = tok_list[off + mi];
      float wt = tok_w[off + mi];
      float* op = out + (size_t)tok * DDIM + nbase + wc * 64 + (lane & 15);
#pragma unroll
      for (int n = 0; n < 4; ++n)
        atomicAdd(op + n * 16, acc[m][n][q] * wt);
    }
}

extern "C" void kernel_launch(void* const* d_in, const int* in_sizes, int n_in,
                              void* d_out, int out_size, void* d_ws, size_t ws_size,
                              hipStream_t stream) {
  const float* x      = (const float*)d_in[0];
  const float* gate_w = (const float*)d_in[1];
  const float* w1     = (const float*)d_in[2];
  const float* w2     = (const float*)d_in[3];
  const float* w3     = (const float*)d_in[4];
  float* out = (float*)d_out;
  char* ws = (char*)d_ws;

  size_t o = 0;
  int* counts  = (int*)(ws + o);
  int* offsets = counts + 8;
  int* cursor  = counts + 16;
  o += 256;
  int*   route_e = (int*)(ws + o);   o += (size_t)TT * 2 * 4;
  float* route_w = (float*)(ws + o); o += (size_t)TT * 2 * 4;
  int*   tok_list = (int*)(ws + o);  o += (size_t)TT * 2 * 4;
  float* tok_w = (float*)(ws + o);   o += (size_t)TT * 2 * 4;
  unsigned short* xbf = (unsigned short*)(ws + o); o += (size_t)TT * DDIM * 2;
  size_t fixed = o;

  const size_t WSZ = (size_t)HDIM * DDIM;
  const size_t wbf_full = (size_t)NEXP * WSZ * 2;
  const size_t gfull = (size_t)TT * 2 * HDIM * 2;

  hipMemsetAsync(counts, 0, 8 * sizeof(int), stream);
  hipMemsetAsync(out, 0, (size_t)TT * DDIM * sizeof(float), stream);
  cvt_bf16_kernel<<<4096, 256, 0, stream>>>(x, xbf, (long)TT * DDIM / 4);
  gate_kernel<<<TT, 256, 0, stream>>>(x, gate_w, route_e, route_w, counts);
  scan_kernel<<<1, 64, 0, stream>>>(counts, offsets, cursor);
  scatter_kernel<<<(TT + 255) / 256, 256, 0, stream>>>(route_e, route_w, cursor, tok_list, tok_w);

  if (ws_size >= fixed + 3 * wbf_full + gfull) {
    unsigned short* w1b = (unsigned short*)(ws + fixed);
    unsigned short* w3b = w1b + NEXP * WSZ;
    unsigned short* w2t = w3b + NEXP * WSZ;
    unsigned short* gbuf = w2t + NEXP * WSZ;
    cvt_bf16_kernel<<<8192, 256, 0, stream>>>(w1, w1b, (long)(NEXP * WSZ / 4));
    cvt_bf16_kernel<<<8192, 256, 0, stream>>>(w3, w3b, (long)(NEXP * WSZ / 4));
    transpose_w2_kernel<<<dim3(HDIM / 64, DDIM / 64, NEXP), 256, 0, stream>>>(w2, w2t, -1);
    gemm1_kernel<<<MT * NT1 * NEXP, 512, 0, stream>>>(
        xbf, w1b, w3b, tok_list, counts, offsets, gbuf, -1);
    gemm2_kernel<<<MT * NT2 * NEXP, 512, 0, stream>>>(
        gbuf, w2t, tok_list, tok_w, counts, offsets, out, -1);
  } else {
    unsigned short* w1b = (unsigned short*)(ws + fixed);
    unsigned short* w3b = w1b + WSZ;
    unsigned short* w2t = w3b + WSZ;
    unsigned short* gbuf = w2t + WSZ;
    for (int e = 0; e < NEXP; ++e) {
      cvt_bf16_kernel<<<4096, 256, 0, stream>>>(w1 + (size_t)e * WSZ, w1b, (long)(WSZ / 4));
      cvt_bf16_kernel<<<4096, 256, 0, stream>>>(w3 + (size_t)e * WSZ, w3b, (long)(WSZ / 4));
      transpose_w2_kernel<<<dim3(HDIM / 64, DDIM / 64, 1), 256, 0, stream>>>(w2, w2t, e);
      gemm1_kernel<<<MT * NT1, 512, 0, stream>>>(
          xbf, w1b, w3b, tok_list, counts, offsets, gbuf, e);
      gemm2_kernel<<<MT * NT2, 512, 0, stream>>>(
          gbuf, w2t, tok_list, tok_w, counts, offsets, out, e);
    }
  }
}

// Round 9
// 2720.250 us; speedup vs baseline: 1.1600x; 1.1600x over previous
//
#include <hip/hip_runtime.h>

#define TT   8192
#define DDIM 2048
#define HDIM 7168
#define NEXP 8
#define MT   32                 // max M-tiles per expert (8192/256)
#define NT1  (HDIM / 128)       // 56 n-tiles for gemm1 (128 h1 + 128 h3 cols each)
#define NT2  (DDIM / 256)       // 8 n-tiles for gemm2

typedef __attribute__((ext_vector_type(8))) short bf16x8;
typedef __attribute__((ext_vector_type(4))) short short4v;
typedef __attribute__((ext_vector_type(4))) float f32x4;

__device__ __forceinline__ unsigned short f2bf(float f) {
  unsigned int u = __builtin_bit_cast(unsigned int, f);
  u += 0x7fffu + ((u >> 16) & 1u);   // RNE
  return (unsigned short)(u >> 16);
}

__device__ __forceinline__ void gload_lds16(const void* gp, void* lp) {
  __builtin_amdgcn_global_load_lds((__attribute__((address_space(1))) void*)gp,
                                   (__attribute__((address_space(3))) void*)lp,
                                   16, 0, 0);
}

__device__ __forceinline__ void mfma16(f32x4& c, bf16x8 a, bf16x8 b) {
  c = __builtin_amdgcn_mfma_f32_16x16x32_bf16(a, b, c, 0, 0, 0);
}

__device__ __forceinline__ void wg_barrier() {
  asm volatile("" ::: "memory");
  __builtin_amdgcn_s_barrier();
  asm volatile("" ::: "memory");
}

// ---- 4-phase schedule, corrected ledger (r8 post-mortem) ----
// LDS per buffer (64KB): A_k0@0 | A_k1@16384 | B_k0@32768 | B_k1@49152; buf1 +65536.
// [256 rows][32 k] bf16 per region, row stride 64B, XOR-swizzled 16B chunks.
// Phase q: {12 ds_reads (af[8] from BA, bfr[4] from BB); stage A+B (4 gloads)
// into the two regions READ IN PHASE q-1 (reads retired at q-1's trailing
// barrier -> overwrite-safe, r5 invariant); barrier; lgkmcnt(0);
// sched_barrier; setprio(1); 32 MFMA; setprio(0); vmcnt; barrier}.
// Stage targets are disjoint from q's own reads (all 4 phases, verified).
// Constant 4 gloads/phase + vmcnt(8) every phase => stage at q landed by end
// of q+2; first read of staged data at q+3 (one phase of margin).
#define PH4(BA, BB, SA, AO, SB, BO, VM)                                      \
  do {                                                                       \
    _Pragma("unroll")                                                        \
    for (int m = 0; m < 8; ++m)                                              \
      af[m] = *(const bf16x8*)(smem + (BA) + rA + m * 1024);                 \
    _Pragma("unroll")                                                        \
    for (int n = 0; n < 4; ++n)                                              \
      bfr[n] = *(const bf16x8*)(smem + (BB) + rB + n * 1024);                \
    if ((SA) >= 0) {                                                         \
      gload_lds16(asrc[0] + (AO), smem + (SA) + wid * 2048);                 \
      gload_lds16(asrc[1] + (AO), smem + (SA) + wid * 2048 + 1024);          \
    }                                                                        \
    if ((SB) >= 0) {                                                         \
      gload_lds16(bsrc[0] + (BO), smem + (SB) + wid * 2048);                 \
      gload_lds16(bsrc[1] + (BO), smem + (SB) + wid * 2048 + 1024);          \
    }                                                                        \
    wg_barrier();                                                            \
    asm volatile("s_waitcnt lgkmcnt(0)" ::: "memory");                       \
    __builtin_amdgcn_sched_barrier(0);                                       \
    __builtin_amdgcn_s_setprio(1);                                           \
    _Pragma("unroll")                                                        \
    for (int n = 0; n < 4; ++n) {                                            \
      _Pragma("unroll")                                                      \
      for (int m = 0; m < 8; ++m)                                            \
        mfma16(acc[m][n], af[m], bfr[n]);                                    \
    }                                                                        \
    __builtin_amdgcn_s_setprio(0);                                           \
    __builtin_amdgcn_sched_barrier(0);                                       \
    if ((VM) == 8) asm volatile("s_waitcnt vmcnt(8)" ::: "memory");          \
    if ((VM) == 4) asm volatile("s_waitcnt vmcnt(4)" ::: "memory");          \
    if ((VM) == 0) asm volatile("s_waitcnt vmcnt(0)" ::: "memory");          \
    wg_barrier();                                                            \
  } while (0)

// Iteration i: K-tile t=2i in buf0, t+1 in buf1; kb = i*256 (bytes along K;
// tile t k0 @kb, k1 @kb+64; t+1 @+128/+192; t+2 @+256/+320; t+3 @+384/+448).
// Reads: P1 b0{A_k0,B_k0}; P2 b0{A_k1,B_k1}; P3 b1{A_k0,B_k0}; P4 b1{A_k1,B_k1}.
// Stages (= regions read in previous phase, with next-needed data):
//  P1 -> b1.A_k1/B_k1 (t+1 k1, kb+192)   [read at P4, 3 phases later]
//  P2 -> b0.A_k0/B_k0 (t+2 k0, kb+256)   [read at next P1]
//  P3 -> b0.A_k1/B_k1 (t+2 k1, kb+320)   [read at next P2]
//  P4 -> b1.A_k0/B_k0 (t+3 k0, kb+384)   [read at next P3]
#define ITER4_FULL(kb)                                                       \
  PH4(0,     32768,  81920, (kb) + 192, 114688, (kb) + 192, 8);              \
  PH4(16384, 49152,  0,     (kb) + 256, 32768,  (kb) + 256, 8);              \
  PH4(65536, 98304,  16384, (kb) + 320, 49152,  (kb) + 320, 8);              \
  PH4(81920, 114688, 65536, (kb) + 384, 98304,  (kb) + 384, 8);

// Last iteration: only P1 stages (final tile's k1).  Sparse issue breaks the
// constant-rate argument, so waits tighten: P1 vm8 (covers P2's operands:
// staged 2 full-rate phases ago + 8 issued since), P2 vm4 (P3's operands:
// only 4 issued after their stage), P3 vm0 (P4's operands: nothing issued
// after), P4 none (drained; epilogue safe after P3's vmcnt(0)).
#define ITER4_LAST(kb)                                                       \
  PH4(0,     32768,  81920, (kb) + 192, 114688, (kb) + 192, 8);              \
  PH4(16384, 49152,  -1,    0,          -1,     0,          4);              \
  PH4(65536, 98304,  -1,    0,          -1,     0,          0);              \
  PH4(81920, 114688, -1,    0,          -1,     0,          -1);

// Prologue: 12 gloads in read order (b0.A_k0, b0.B_k0, b0.A_k1, b0.B_k1,
// b1.A_k0, b1.B_k0); vmcnt(8) retires the oldest 4 = P1's operands.
// P2/P3 operands retire via P1/P2's vmcnt(8) (8 issued after each).
#define PROLOGUE()                                                           \
  do {                                                                       \
    gload_lds16(asrc[0] + 0,   smem + 0      + wid * 2048);                  \
    gload_lds16(asrc[1] + 0,   smem + 0      + wid * 2048 + 1024);           \
    gload_lds16(bsrc[0] + 0,   smem + 32768  + wid * 2048);                  \
    gload_lds16(bsrc[1] + 0,   smem + 32768  + wid * 2048 + 1024);           \
    gload_lds16(asrc[0] + 64,  smem + 16384  + wid * 2048);                  \
    gload_lds16(asrc[1] + 64,  smem + 16384  + wid * 2048 + 1024);           \
    gload_lds16(bsrc[0] + 64,  smem + 49152  + wid * 2048);                  \
    gload_lds16(bsrc[1] + 64,  smem + 49152  + wid * 2048 + 1024);           \
    gload_lds16(asrc[0] + 128, smem + 65536  + wid * 2048);                  \
    gload_lds16(asrc[1] + 128, smem + 65536  + wid * 2048 + 1024);           \
    gload_lds16(bsrc[0] + 128, smem + 98304  + wid * 2048);                  \
    gload_lds16(bsrc[1] + 128, smem + 98304  + wid * 2048 + 1024);           \
    asm volatile("s_waitcnt vmcnt(8)" ::: "memory");                         \
    wg_barrier();                                                            \
  } while (0)

// ---------------- fp32 -> bf16 elementwise ----------------
__global__ __launch_bounds__(256) void cvt_bf16_kernel(const float* __restrict__ src,
                                                       unsigned short* __restrict__ dst,
                                                       long n4) {
  long i = (long)blockIdx.x * 256 + threadIdx.x;
  long stride = (long)gridDim.x * 256;
  for (; i < n4; i += stride) {
    float4 v = ((const float4*)src)[i];
    short4v s;
    s[0] = (short)f2bf(v.x); s[1] = (short)f2bf(v.y);
    s[2] = (short)f2bf(v.z); s[3] = (short)f2bf(v.w);
    ((short4v*)dst)[i] = s;
  }
}

// ---------------- gate ----------------
__global__ __launch_bounds__(256) void gate_kernel(const float* __restrict__ x,
                                                   const float* __restrict__ gw,
                                                   int* __restrict__ route_e,
                                                   float* __restrict__ route_w,
                                                   int* __restrict__ counts) {
  int t = blockIdx.x;
  int tid = threadIdx.x;
  const float* xr = x + (size_t)t * DDIM;
  float p[NEXP];
#pragma unroll
  for (int e = 0; e < NEXP; ++e) p[e] = 0.f;
#pragma unroll
  for (int c = 0; c < DDIM / (256 * 4); ++c) {
    int d = (c * 256 + tid) * 4;
    float4 xv = *(const float4*)(xr + d);
#pragma unroll
    for (int e = 0; e < NEXP; ++e) {
      float4 wv = *(const float4*)(gw + (size_t)e * DDIM + d);
      p[e] += xv.x * wv.x + xv.y * wv.y + xv.z * wv.z + xv.w * wv.w;
    }
  }
  __shared__ float red[NEXP][4];
  int lane = tid & 63, wid = tid >> 6;
#pragma unroll
  for (int e = 0; e < NEXP; ++e) {
    float v = p[e];
    for (int o = 32; o > 0; o >>= 1) v += __shfl_down(v, o);
    if (lane == 0) red[e][wid] = v;
  }
  __syncthreads();
  if (tid == 0) {
    float lg[NEXP];
#pragma unroll
    for (int e = 0; e < NEXP; ++e) lg[e] = red[e][0] + red[e][1] + red[e][2] + red[e][3];
    int i0 = 0;
#pragma unroll
    for (int e = 1; e < NEXP; ++e) if (lg[e] > lg[i0]) i0 = e;
    int i1 = -1;
#pragma unroll
    for (int e = 0; e < NEXP; ++e) {
      if (e == i0) continue;
      if (i1 < 0 || lg[e] > lg[i1]) i1 = e;
    }
    float w0 = 1.f / (1.f + __expf(lg[i1] - lg[i0]));
    float w1 = 1.f - w0;
    route_e[t * 2 + 0] = i0;  route_e[t * 2 + 1] = i1;
    route_w[t * 2 + 0] = w0;  route_w[t * 2 + 1] = w1;
    atomicAdd(&counts[i0], 1);
    atomicAdd(&counts[i1], 1);
  }
}

__global__ void scan_kernel(const int* __restrict__ counts, int* __restrict__ offsets,
                            int* __restrict__ cursor) {
  if (threadIdx.x == 0 && blockIdx.x == 0) {
    int o = 0;
    for (int e = 0; e < NEXP; ++e) { offsets[e] = o; cursor[e] = o; o += counts[e]; }
  }
}

__global__ __launch_bounds__(256) void scatter_kernel(const int* __restrict__ route_e,
                                                      const float* __restrict__ route_w,
                                                      int* __restrict__ cursor,
                                                      int* __restrict__ tok_list,
                                                      float* __restrict__ tok_w) {
  int t = blockIdx.x * 256 + threadIdx.x;
  if (t >= TT) return;
#pragma unroll
  for (int s = 0; s < 2; ++s) {
    int e = route_e[t * 2 + s];
    int p = atomicAdd(&cursor[e], 1);
    tok_list[p] = t;
    tok_w[p] = route_w[t * 2 + s];
  }
}

// ---------------- w2 [H,D] fp32 -> w2t [D,H] bf16 ----------------
__global__ __launch_bounds__(256) void transpose_w2_kernel(const float* __restrict__ w2,
                                                           unsigned short* __restrict__ w2t,
                                                           int expert_fixed) {
  int e = expert_fixed >= 0 ? expert_fixed : (int)blockIdx.z;
  const float* src = w2 + (size_t)e * HDIM * DDIM;
  unsigned short* dst = w2t + (expert_fixed >= 0 ? (size_t)0 : (size_t)e * DDIM * HDIM);
  int h0 = blockIdx.x * 64, d0 = blockIdx.y * 64;
  __shared__ __align__(8) unsigned short tile[64 * 66];
  int tid = threadIdx.x;
  int hr = tid >> 2;
#pragma unroll
  for (int j = 0; j < 4; ++j) {
    int f4 = (tid & 3) + j * 4;
    float4 v = *(const float4*)(src + (size_t)(h0 + hr) * DDIM + d0 + f4 * 4);
    unsigned int lo = (unsigned int)f2bf(v.x) | ((unsigned int)f2bf(v.y) << 16);
    unsigned int hi = (unsigned int)f2bf(v.z) | ((unsigned int)f2bf(v.w) << 16);
    char* bp = (char*)tile + hr * 132 + f4 * 8;
    *(unsigned int*)bp = lo;
    *(unsigned int*)(bp + 4) = hi;
  }
  __syncthreads();
  int dr = tid >> 2;
  int hbase = (tid & 3) * 16;
  unsigned short vals[16];
#pragma unroll
  for (int i = 0; i < 16; ++i)
    vals[i] = *(unsigned short*)((char*)tile + (hbase + i) * 132 + dr * 2);
  unsigned short* op = dst + (size_t)(d0 + dr) * HDIM + h0 + hbase;
#pragma unroll
  for (int j = 0; j < 4; ++j) {
    short4v s;
    s[0] = (short)vals[j * 4 + 0]; s[1] = (short)vals[j * 4 + 1];
    s[2] = (short)vals[j * 4 + 2]; s[3] = (short)vals[j * 4 + 3];
    *(short4v*)(op + j * 4) = s;
  }
}

// =====================================================================
// GEMM1: g = silu(Xe w1^T) * (Xe w3^T); 256x256 tile (128 w1 + 128 w3
// cols), BK=64, 8 waves, 4-phase corrected-ledger schedule.
// =====================================================================
__global__ __launch_bounds__(512, 2) void gemm1_kernel(
    const unsigned short* __restrict__ xbf, const unsigned short* __restrict__ w1b,
    const unsigned short* __restrict__ w3b, const int* __restrict__ tok_list,
    const int* __restrict__ counts, const int* __restrict__ offsets,
    unsigned short* __restrict__ g, int expert_fixed) {
  __shared__ __align__(16) char smem[133120];   // 128KB staging + epi hb[256][130] f32
  constexpr int NI = DDIM / 128;                // 16 iterations (2 K-tiles each)

  int nwg = gridDim.x;
  int orig = blockIdx.x;
  int wg = (orig & 7) * (nwg >> 3) + (orig >> 3);   // bijective XCD swizzle (nwg%8==0)
  int mt = wg & (MT - 1);
  int rem = wg >> 5;
  int nt = rem % NT1;
  int e = expert_fixed >= 0 ? expert_fixed : rem / NT1;

  int cnt = counts[e];
  int mbase = mt * 256;
  if (mbase >= cnt) return;
  int off = offsets[e];
  int gshift = expert_fixed >= 0 ? 0 : off;
  int rows = cnt - mbase; if (rows > 256) rows = 256;

  const unsigned short* w1e = expert_fixed >= 0 ? w1b : w1b + (size_t)e * HDIM * DDIM;
  const unsigned short* w3e = expert_fixed >= 0 ? w3b : w3b + (size_t)e * HDIM * DDIM;

  int tid = threadIdx.x, lane = tid & 63, wid = tid >> 6;
  int wr = wid >> 2, wc = wid & 3;

  // staging sources: per half-tile gload j, wave covers rows wid*32+j*16+(lane>>2)
  int r16 = lane >> 2;
  int csrc = (lane & 3) ^ ((lane >> 3) & 3);    // pre-swizzled source chunk
  const char* asrc[2]; const char* bsrc[2];
#pragma unroll
  for (int j = 0; j < 2; ++j) {
    int r = wid * 32 + j * 16 + r16;
    int m = mbase + r; if (m > cnt - 1) m = cnt - 1;
    int tok = tok_list[off + m];
    asrc[j] = (const char*)xbf + (size_t)tok * (DDIM * 2) + csrc * 16;
    const char* base = (r < 128)
        ? (const char*)w1e + (size_t)(nt * 128 + r) * (DDIM * 2)
        : (const char*)w3e + (size_t)(nt * 128 + r - 128) * (DDIM * 2);
    bsrc[j] = base + csrc * 16;
  }
  // fragment read offsets (lane-constant)
  int rA = (wr * 128 + (lane & 15)) * 64 + (((lane >> 4) ^ ((lane >> 1) & 3)) * 16);
  int rB = (wc * 64  + (lane & 15)) * 64 + (((lane >> 4) ^ ((lane >> 1) & 3)) * 16);

  f32x4 zv = {0.f, 0.f, 0.f, 0.f};
  f32x4 acc[8][4];
#pragma unroll
  for (int m = 0; m < 8; ++m)
#pragma unroll
    for (int n = 0; n < 4; ++n) acc[m][n] = zv;
  bf16x8 af[8], bfr[4];

  PROLOGUE();
#pragma unroll 1
  for (int i = 0; i < NI - 1; ++i) {
    size_t kb = (size_t)i * 256;
    ITER4_FULL(kb);
  }
  {
    size_t kb = (size_t)(NI - 1) * 256;
    ITER4_LAST(kb);
  }

  // ---- epilogue: h1 (wc<2) -> LDS; h3 (wc>=2) computes g = silu(h1)*h3 ----
  float* hb = (float*)smem;                       // [256][130] f32
  if (wc < 2) {
#pragma unroll
    for (int m = 0; m < 8; ++m)
#pragma unroll
      for (int q = 0; q < 4; ++q) {
        int row = wr * 128 + m * 16 + (lane >> 4) * 4 + q;
        int col = wc * 64 + (lane & 15);
#pragma unroll
        for (int n = 0; n < 4; ++n)
          hb[row * 130 + col + n * 16] = acc[m][n][q];
      }
  }
  asm volatile("s_waitcnt lgkmcnt(0)" ::: "memory");
  wg_barrier();
  if (wc >= 2) {
#pragma unroll
    for (int m = 0; m < 8; ++m)
#pragma unroll
      for (int q = 0; q < 4; ++q) {
        int row = wr * 128 + m * 16 + (lane >> 4) * 4 + q;
        if (row >= rows) continue;
        size_t grow = (size_t)(mbase + row + gshift);
        int colbase = (wc - 2) * 64 + (lane & 15);
        unsigned short* gp = g + grow * HDIM + nt * 128 + colbase;
#pragma unroll
        for (int n = 0; n < 4; ++n) {
          float h1 = hb[row * 130 + colbase + n * 16];
          float h3 = acc[m][n][q];
          float gv = (h1 / (1.f + __expf(-h1))) * h3;
          gp[n * 16] = f2bf(gv);
        }
      }
  }
}

// =====================================================================
// GEMM2: out += wt * (g @ w2) via w2t, same 4-phase schedule, atomics.
// =====================================================================
__global__ __launch_bounds__(512, 2) void gemm2_kernel(
    const unsigned short* __restrict__ g, const unsigned short* __restrict__ w2t,
    const int* __restrict__ tok_list, const float* __restrict__ tok_w,
    const int* __restrict__ counts, const int* __restrict__ offsets,
    float* __restrict__ out, int expert_fixed) {
  __shared__ __align__(16) char smem[131072];
  constexpr int NI = HDIM / 128;                // 56 iterations

  int nwg = gridDim.x;
  int orig = blockIdx.x;
  int wg = (orig & 7) * (nwg >> 3) + (orig >> 3);
  int mt = wg & (MT - 1);
  int rem = wg >> 5;
  int nt = rem % NT2;
  int e = expert_fixed >= 0 ? expert_fixed : rem / NT2;

  int cnt = counts[e];
  int mbase = mt * 256;
  if (mbase >= cnt) return;
  int off = offsets[e];
  int gshift = expert_fixed >= 0 ? 0 : off;
  int nbase = nt * 256;
  int rows = cnt - mbase; if (rows > 256) rows = 256;
  const unsigned short* w2te = w2t + (expert_fixed >= 0 ? (size_t)0 : (size_t)e * DDIM * HDIM);

  int tid = threadIdx.x, lane = tid & 63, wid = tid >> 6;
  int wr = wid >> 2, wc = wid & 3;

  int r16 = lane >> 2;
  int csrc = (lane & 3) ^ ((lane >> 3) & 3);
  const char* asrc[2]; const char* bsrc[2];
#pragma unroll
  for (int j = 0; j < 2; ++j) {
    int r = wid * 32 + j * 16 + r16;
    int m = mbase + r; if (m > cnt - 1) m = cnt - 1;
    asrc[j] = (const char*)g + (size_t)(m + gshift) * (HDIM * 2) + csrc * 16;
    bsrc[j] = (const char*)w2te + (size_t)(nbase + r) * (HDIM * 2) + csrc * 16;
  }
  int rA = (wr * 128 + (lane & 15)) * 64 + (((lane >> 4) ^ ((lane >> 1) & 3)) * 16);
  int rB = (wc * 64  + (lane & 15)) * 64 + (((lane >> 4) ^ ((lane >> 1) & 3)) * 16);

  f32x4 zv = {0.f, 0.f, 0.f, 0.f};
  f32x4 acc[8][4];
#pragma unroll
  for (int m = 0; m < 8; ++m)
#pragma unroll
    for (int n = 0; n < 4; ++n) acc[m][n] = zv;
  bf16x8 af[8], bfr[4];

  PROLOGUE();
#pragma unroll 1
  for (int i = 0; i < NI - 1; ++i) {
    size_t kb = (size_t)i * 256;
    ITER4_FULL(kb);
  }
  {
    size_t kb = (size_t)(NI - 1) * 256;
    ITER4_LAST(kb);
  }

#pragma unroll
  for (int m = 0; m < 8; ++m)
#pragma unroll
    for (int q = 0; q < 4; ++q) {
      int row = wr * 128 + m * 16 + (lane >> 4) * 4 + q;
      if (row >= rows) continue;
      int mi = mbase + row;
      int tok = tok_list[off + mi];
      float wt = tok_w[off + mi];
      float* op = out + (size_t)tok * DDIM + nbase + wc * 64 + (lane & 15);
#pragma unroll
      for (int n = 0; n < 4; ++n)
        atomicAdd(op + n * 16, acc[m][n][q] * wt);
    }
}

extern "C" void kernel_launch(void* const* d_in, const int* in_sizes, int n_in,
                              void* d_out, int out_size, void* d_ws, size_t ws_size,
                              hipStream_t stream) {
  const float* x      = (const float*)d_in[0];
  const float* gate_w = (const float*)d_in[1];
  const float* w1     = (const float*)d_in[2];
  const float* w2     = (const float*)d_in[3];
  const float* w3     = (const float*)d_in[4];
  float* out = (float*)d_out;
  char* ws = (char*)d_ws;

  size_t o = 0;
  int* counts  = (int*)(ws + o);
  int* offsets = counts + 8;
  int* cursor  = counts + 16;
  o += 256;
  int*   route_e = (int*)(ws + o);   o += (size_t)TT * 2 * 4;
  float* route_w = (float*)(ws + o); o += (size_t)TT * 2 * 4;
  int*   tok_list = (int*)(ws + o);  o += (size_t)TT * 2 * 4;
  float* tok_w = (float*)(ws + o);   o += (size_t)TT * 2 * 4;
  unsigned short* xbf = (unsigned short*)(ws + o); o += (size_t)TT * DDIM * 2;
  size_t fixed = o;

  const size_t WSZ = (size_t)HDIM * DDIM;
  const size_t wbf_full = (size_t)NEXP * WSZ * 2;
  const size_t gfull = (size_t)TT * 2 * HDIM * 2;

  hipMemsetAsync(counts, 0, 8 * sizeof(int), stream);
  hipMemsetAsync(out, 0, (size_t)TT * DDIM * sizeof(float), stream);
  cvt_bf16_kernel<<<4096, 256, 0, stream>>>(x, xbf, (long)TT * DDIM / 4);
  gate_kernel<<<TT, 256, 0, stream>>>(x, gate_w, route_e, route_w, counts);
  scan_kernel<<<1, 64, 0, stream>>>(counts, offsets, cursor);
  scatter_kernel<<<(TT + 255) / 256, 256, 0, stream>>>(route_e, route_w, cursor, tok_list, tok_w);

  if (ws_size >= fixed + 3 * wbf_full + gfull) {
    unsigned short* w1b = (unsigned short*)(ws + fixed);
    unsigned short* w3b = w1b + NEXP * WSZ;
    unsigned short* w2t = w3b + NEXP * WSZ;
    unsigned short* gbuf = w2t + NEXP * WSZ;
    cvt_bf16_kernel<<<8192, 256, 0, stream>>>(w1, w1b, (long)(NEXP * WSZ / 4));
    cvt_bf16_kernel<<<8192, 256, 0, stream>>>(w3, w3b, (long)(NEXP * WSZ / 4));
    transpose_w2_kernel<<<dim3(HDIM / 64, DDIM / 64, NEXP), 256, 0, stream>>>(w2, w2t, -1);
    gemm1_kernel<<<MT * NT1 * NEXP, 512, 0, stream>>>(
        xbf, w1b, w3b, tok_list, counts, offsets, gbuf, -1);
    gemm2_kernel<<<MT * NT2 * NEXP, 512, 0, stream>>>(
        gbuf, w2t, tok_list, tok_w, counts, offsets, out, -1);
  } else {
    unsigned short* w1b = (unsigned short*)(ws + fixed);
    unsigned short* w3b = w1b + WSZ;
    unsigned short* w2t = w3b + WSZ;
    unsigned short* gbuf = w2t + WSZ;
    for (int e = 0; e < NEXP; ++e) {
      cvt_bf16_kernel<<<4096, 256, 0, stream>>>(w1 + (size_t)e * WSZ, w1b, (long)(WSZ / 4));
      cvt_bf16_kernel<<<4096, 256, 0, stream>>>(w3 + (size_t)e * WSZ, w3b, (long)(WSZ / 4));
      transpose_w2_kernel<<<dim3(HDIM / 64, DDIM / 64, 1), 256, 0, stream>>>(w2, w2t, e);
      gemm1_kernel<<<MT * NT1, 512, 0, stream>>>(
          xbf, w1b, w3b, tok_list, counts, offsets, gbuf, e);
      gemm2_kernel<<<MT * NT2, 512, 0, stream>>>(
          gbuf, w2t, tok_list, tok_w, counts, offsets, out, e);
    }
  }
}

// Round 10
// 2475.058 us; speedup vs baseline: 1.2749x; 1.0991x over previous
//
#include <hip/hip_runtime.h>

#define TT   8192
#define DDIM 2048
#define HDIM 7168
#define NEXP 8
#define MT   32                 // max M-tiles per expert (8192/256)
#define NT1  (HDIM / 128)       // 56 n-tiles for gemm1 (128 h1 + 128 h3 cols each)
#define NT2  (DDIM / 256)       // 8 n-tiles for gemm2

typedef __attribute__((ext_vector_type(8))) short bf16x8;
typedef __attribute__((ext_vector_type(8))) short short8v;
typedef __attribute__((ext_vector_type(4))) short short4v;
typedef __attribute__((ext_vector_type(4))) float f32x4;

__device__ __forceinline__ unsigned short f2bf(float f) {
  unsigned int u = __builtin_bit_cast(unsigned int, f);
  u += 0x7fffu + ((u >> 16) & 1u);   // RNE
  return (unsigned short)(u >> 16);
}

__device__ __forceinline__ void gload_lds16(const void* gp, void* lp) {
  __builtin_amdgcn_global_load_lds((__attribute__((address_space(1))) void*)gp,
                                   (__attribute__((address_space(3))) void*)lp,
                                   16, 0, 0);
}

__device__ __forceinline__ void mfma16(f32x4& c, bf16x8 a, bf16x8 b) {
  c = __builtin_amdgcn_mfma_f32_16x16x32_bf16(a, b, c, 0, 0, 0);
}

__device__ __forceinline__ void wg_barrier() {
  asm volatile("" ::: "memory");
  __builtin_amdgcn_s_barrier();
  asm volatile("" ::: "memory");
}

// ---- 8-phase schedule (r5/r6-validated ledger), compiler-scheduled waits ----
// LDS per buffer (64KB): A_k0 | A_k1 | B_k0 | B_k1, each [256 rows][32 k] bf16
// (row stride 64B, XOR-swizzled 16B chunks).  buf0 at 0, buf1 at 65536.
// CHANGE vs r6: no forced lgkmcnt(0)/sched_barrier before the MFMAs — plain
// LDS loads + builtin MFMA let the compiler emit fine-grained per-operand
// lgkmcnt chains (m97), so waves stagger into MFMA as their reads retire
// instead of all draining first.  Safety unchanged: every read is consumed
// by an MFMA before barrier-2 (compiler waits retire reads pre-consumer), so
// barrier-2 remains the "reads retired" checkpoint for next-phase stages.
// vmcnt(6) at phases 4/8 only (2 loads x 3 half-tiles in flight).
#define PH(H, BA, BB, RDB, STG, SRCP, SOFF, VM)                              \
  do {                                                                       \
    if (RDB) {                                                               \
      _Pragma("unroll")                                                      \
      for (int n = 0; n < 4; ++n)                                            \
        bfr[n] = *(const bf16x8*)(smem + (BB) + rB + n * 1024);              \
    }                                                                        \
    _Pragma("unroll")                                                        \
    for (int m = 0; m < 4; ++m)                                              \
      af[m] = *(const bf16x8*)(smem + (BA) + rA + ((H) + m) * 1024);         \
    if ((STG) >= 0) {                                                        \
      gload_lds16(SRCP[0] + (SOFF), smem + (STG) + wid * 2048);              \
      gload_lds16(SRCP[1] + (SOFF), smem + (STG) + wid * 2048 + 1024);       \
    }                                                                        \
    wg_barrier();                                                            \
    __builtin_amdgcn_s_setprio(1);                                           \
    _Pragma("unroll")                                                        \
    for (int n = 0; n < 4; ++n) {                                            \
      _Pragma("unroll")                                                      \
      for (int m = 0; m < 4; ++m)                                            \
        mfma16(acc[(H) + m][n], af[m], bfr[n]);                              \
    }                                                                        \
    __builtin_amdgcn_s_setprio(0);                                           \
    if ((VM) == 6) asm volatile("s_waitcnt vmcnt(6)" ::: "memory");          \
    if ((VM) == 0) asm volatile("s_waitcnt vmcnt(0)" ::: "memory");          \
    wg_barrier();                                                            \
  } while (0)

// Full iteration i (tiles t=2i in buf0, t+1 in buf1); kb = i*256 bytes.
// Stage targets (r5-validated ledger): p1->buf1.A_k1(t+1), p2->buf0.B_k0(t+2),
// p3->buf0.A_k0(t+2), p4->buf0.B_k1(t+2)+vm6, p5->buf0.A_k1(t+2),
// p6->buf1.B_k0(t+3), p7->buf1.A_k0(t+3), p8->buf1.B_k1(t+3)+vm6.
#define ITER_FULL(kb)                                                        \
  PH(0, 0,     32768,  1, 81920,  asrc, (kb) + 192, -1);                     \
  PH(4, 0,     32768,  0, 32768,  bsrc, (kb) + 256, -1);                     \
  PH(0, 16384, 49152,  1, 0,      asrc, (kb) + 256, -1);                     \
  PH(4, 16384, 49152,  0, 49152,  bsrc, (kb) + 320,  6);                     \
  PH(0, 65536, 98304,  1, 16384,  asrc, (kb) + 320, -1);                     \
  PH(4, 65536, 98304,  0, 98304,  bsrc, (kb) + 384, -1);                     \
  PH(0, 81920, 114688, 1, 65536,  asrc, (kb) + 384, -1);                     \
  PH(4, 81920, 114688, 0, 114688, bsrc, (kb) + 448,  6);

// Last iteration: only p1 stages (A_k1 of final tile); vmcnt(0) at p4 drains.
#define ITER_LAST(kb)                                                        \
  PH(0, 0,     32768,  1, 81920,  asrc, (kb) + 192, -1);                     \
  PH(4, 0,     32768,  0, -1,     asrc, 0,          -1);                     \
  PH(0, 16384, 49152,  1, -1,     asrc, 0,          -1);                     \
  PH(4, 16384, 49152,  0, -1,     asrc, 0,           0);                     \
  PH(0, 65536, 98304,  1, -1,     asrc, 0,          -1);                     \
  PH(4, 65536, 98304,  0, -1,     asrc, 0,          -1);                     \
  PH(0, 81920, 114688, 1, -1,     asrc, 0,          -1);                     \
  PH(4, 81920, 114688, 0, -1,     asrc, 0,          -1);

// Prologue: tile0's 4 half-tiles then 3 half-tiles of tile1, in exact issue
// order; vmcnt(6) forces the oldest 8 loads (= all of tile 0) retired.
#define PROLOGUE()                                                           \
  do {                                                                       \
    gload_lds16(asrc[0] + 0,   smem + 0      + wid * 2048);                  \
    gload_lds16(asrc[1] + 0,   smem + 0      + wid * 2048 + 1024);           \
    gload_lds16(bsrc[0] + 0,   smem + 32768  + wid * 2048);                  \
    gload_lds16(bsrc[1] + 0,   smem + 32768  + wid * 2048 + 1024);           \
    gload_lds16(asrc[0] + 64,  smem + 16384  + wid * 2048);                  \
    gload_lds16(asrc[1] + 64,  smem + 16384  + wid * 2048 + 1024);           \
    gload_lds16(bsrc[0] + 64,  smem + 49152  + wid * 2048);                  \
    gload_lds16(bsrc[1] + 64,  smem + 49152  + wid * 2048 + 1024);           \
    gload_lds16(bsrc[0] + 128, smem + 98304  + wid * 2048);                  \
    gload_lds16(bsrc[1] + 128, smem + 98304  + wid * 2048 + 1024);           \
    gload_lds16(asrc[0] + 128, smem + 65536  + wid * 2048);                  \
    gload_lds16(asrc[1] + 128, smem + 65536  + wid * 2048 + 1024);           \
    gload_lds16(bsrc[0] + 192, smem + 114688 + wid * 2048);                  \
    gload_lds16(bsrc[1] + 192, smem + 114688 + wid * 2048 + 1024);           \
    asm volatile("s_waitcnt vmcnt(6)" ::: "memory");                         \
    wg_barrier();                                                            \
  } while (0)

// ---------------- fp32 -> bf16 elementwise (8 elems/thread, 16B store) ----
__global__ __launch_bounds__(256) void cvt_bf16_kernel(const float* __restrict__ src,
                                                       unsigned short* __restrict__ dst,
                                                       long n8) {
  long i = (long)blockIdx.x * 256 + threadIdx.x;
  long stride = (long)gridDim.x * 256;
  for (; i < n8; i += stride) {
    float4 a = ((const float4*)src)[i * 2];
    float4 b = ((const float4*)src)[i * 2 + 1];
    short8v s;
    s[0] = (short)f2bf(a.x); s[1] = (short)f2bf(a.y);
    s[2] = (short)f2bf(a.z); s[3] = (short)f2bf(a.w);
    s[4] = (short)f2bf(b.x); s[5] = (short)f2bf(b.y);
    s[6] = (short)f2bf(b.z); s[7] = (short)f2bf(b.w);
    ((short8v*)dst)[i] = s;
  }
}

// ---------------- gate ----------------
__global__ __launch_bounds__(256) void gate_kernel(const float* __restrict__ x,
                                                   const float* __restrict__ gw,
                                                   int* __restrict__ route_e,
                                                   float* __restrict__ route_w,
                                                   int* __restrict__ counts) {
  int t = blockIdx.x;
  int tid = threadIdx.x;
  const float* xr = x + (size_t)t * DDIM;
  float p[NEXP];
#pragma unroll
  for (int e = 0; e < NEXP; ++e) p[e] = 0.f;
#pragma unroll
  for (int c = 0; c < DDIM / (256 * 4); ++c) {
    int d = (c * 256 + tid) * 4;
    float4 xv = *(const float4*)(xr + d);
#pragma unroll
    for (int e = 0; e < NEXP; ++e) {
      float4 wv = *(const float4*)(gw + (size_t)e * DDIM + d);
      p[e] += xv.x * wv.x + xv.y * wv.y + xv.z * wv.z + xv.w * wv.w;
    }
  }
  __shared__ float red[NEXP][4];
  int lane = tid & 63, wid = tid >> 6;
#pragma unroll
  for (int e = 0; e < NEXP; ++e) {
    float v = p[e];
    for (int o = 32; o > 0; o >>= 1) v += __shfl_down(v, o);
    if (lane == 0) red[e][wid] = v;
  }
  __syncthreads();
  if (tid == 0) {
    float lg[NEXP];
#pragma unroll
    for (int e = 0; e < NEXP; ++e) lg[e] = red[e][0] + red[e][1] + red[e][2] + red[e][3];
    int i0 = 0;
#pragma unroll
    for (int e = 1; e < NEXP; ++e) if (lg[e] > lg[i0]) i0 = e;
    int i1 = -1;
#pragma unroll
    for (int e = 0; e < NEXP; ++e) {
      if (e == i0) continue;
      if (i1 < 0 || lg[e] > lg[i1]) i1 = e;
    }
    float w0 = 1.f / (1.f + __expf(lg[i1] - lg[i0]));
    float w1 = 1.f - w0;
    route_e[t * 2 + 0] = i0;  route_e[t * 2 + 1] = i1;
    route_w[t * 2 + 0] = w0;  route_w[t * 2 + 1] = w1;
    atomicAdd(&counts[i0], 1);
    atomicAdd(&counts[i1], 1);
  }
}

__global__ void scan_kernel(const int* __restrict__ counts, int* __restrict__ offsets,
                            int* __restrict__ cursor) {
  if (threadIdx.x == 0 && blockIdx.x == 0) {
    int o = 0;
    for (int e = 0; e < NEXP; ++e) { offsets[e] = o; cursor[e] = o; o += counts[e]; }
  }
}

__global__ __launch_bounds__(256) void scatter_kernel(const int* __restrict__ route_e,
                                                      const float* __restrict__ route_w,
                                                      int* __restrict__ cursor,
                                                      int* __restrict__ tok_list,
                                                      float* __restrict__ tok_w) {
  int t = blockIdx.x * 256 + threadIdx.x;
  if (t >= TT) return;
#pragma unroll
  for (int s = 0; s < 2; ++s) {
    int e = route_e[t * 2 + s];
    int p = atomicAdd(&cursor[e], 1);
    tok_list[p] = t;
    tok_w[p] = route_w[t * 2 + s];
  }
}

// ---------------- w2 [H,D] fp32 -> w2t [D,H] bf16 ----------------
__global__ __launch_bounds__(256) void transpose_w2_kernel(const float* __restrict__ w2,
                                                           unsigned short* __restrict__ w2t,
                                                           int expert_fixed) {
  int e = expert_fixed >= 0 ? expert_fixed : (int)blockIdx.z;
  const float* src = w2 + (size_t)e * HDIM * DDIM;
  unsigned short* dst = w2t + (expert_fixed >= 0 ? (size_t)0 : (size_t)e * DDIM * HDIM);
  int h0 = blockIdx.x * 64, d0 = blockIdx.y * 64;
  __shared__ __align__(8) unsigned short tile[64 * 66];
  int tid = threadIdx.x;
  int hr = tid >> 2;
#pragma unroll
  for (int j = 0; j < 4; ++j) {
    int f4 = (tid & 3) + j * 4;
    float4 v = *(const float4*)(src + (size_t)(h0 + hr) * DDIM + d0 + f4 * 4);
    unsigned int lo = (unsigned int)f2bf(v.x) | ((unsigned int)f2bf(v.y) << 16);
    unsigned int hi = (unsigned int)f2bf(v.z) | ((unsigned int)f2bf(v.w) << 16);
    char* bp = (char*)tile + hr * 132 + f4 * 8;
    *(unsigned int*)bp = lo;
    *(unsigned int*)(bp + 4) = hi;
  }
  __syncthreads();
  int dr = tid >> 2;
  int hbase = (tid & 3) * 16;
  unsigned short vals[16];
#pragma unroll
  for (int i = 0; i < 16; ++i)
    vals[i] = *(unsigned short*)((char*)tile + (hbase + i) * 132 + dr * 2);
  unsigned short* op = dst + (size_t)(d0 + dr) * HDIM + h0 + hbase;
  short8v s0, s1;
#pragma unroll
  for (int i = 0; i < 8; ++i) { s0[i] = (short)vals[i]; s1[i] = (short)vals[i + 8]; }
  *(short8v*)(op) = s0;
  *(short8v*)(op + 8) = s1;
}

// =====================================================================
// GEMM1: g = silu(Xe w1^T) * (Xe w3^T); 256x256 tile (128 w1 + 128 w3
// cols), BK=64, 8 waves, 8-phase counted-vmcnt, compiler-scheduled lgkm.
// =====================================================================
__global__ __launch_bounds__(512, 2) void gemm1_kernel(
    const unsigned short* __restrict__ xbf, const unsigned short* __restrict__ w1b,
    const unsigned short* __restrict__ w3b, const int* __restrict__ tok_list,
    const int* __restrict__ counts, const int* __restrict__ offsets,
    unsigned short* __restrict__ g, int expert_fixed) {
  __shared__ __align__(16) char smem[133120];   // 128KB staging + epi hb[256][130] f32
  constexpr int NI = DDIM / 128;                // 16 iterations (2 K-tiles each)

  int nwg = gridDim.x;
  int orig = blockIdx.x;
  int wg = (orig & 7) * (nwg >> 3) + (orig >> 3);   // bijective XCD swizzle (nwg%8==0)
  int mt = wg & (MT - 1);
  int rem = wg >> 5;
  int nt = rem % NT1;
  int e = expert_fixed >= 0 ? expert_fixed : rem / NT1;

  int cnt = counts[e];
  int mbase = mt * 256;
  if (mbase >= cnt) return;
  int off = offsets[e];
  int gshift = expert_fixed >= 0 ? 0 : off;
  int rows = cnt - mbase; if (rows > 256) rows = 256;

  const unsigned short* w1e = expert_fixed >= 0 ? w1b : w1b + (size_t)e * HDIM * DDIM;
  const unsigned short* w3e = expert_fixed >= 0 ? w3b : w3b + (size_t)e * HDIM * DDIM;

  int tid = threadIdx.x, lane = tid & 63, wid = tid >> 6;
  int wr = wid >> 2, wc = wid & 3;

  // staging sources: per half-tile gload j, wave covers rows wid*32+j*16+(lane>>2)
  int r16 = lane >> 2;
  int csrc = (lane & 3) ^ ((lane >> 3) & 3);    // pre-swizzled source chunk
  const char* asrc[2]; const char* bsrc[2];
#pragma unroll
  for (int j = 0; j < 2; ++j) {
    int r = wid * 32 + j * 16 + r16;
    int m = mbase + r; if (m > cnt - 1) m = cnt - 1;
    int tok = tok_list[off + m];
    asrc[j] = (const char*)xbf + (size_t)tok * (DDIM * 2) + csrc * 16;
    const char* base = (r < 128)
        ? (const char*)w1e + (size_t)(nt * 128 + r) * (DDIM * 2)
        : (const char*)w3e + (size_t)(nt * 128 + r - 128) * (DDIM * 2);
    bsrc[j] = base + csrc * 16;
  }
  // fragment read offsets (lane-constant)
  int rA = (wr * 128 + (lane & 15)) * 64 + (((lane >> 4) ^ ((lane >> 1) & 3)) * 16);
  int rB = (wc * 64  + (lane & 15)) * 64 + (((lane >> 4) ^ ((lane >> 1) & 3)) * 16);

  f32x4 zv = {0.f, 0.f, 0.f, 0.f};
  f32x4 acc[8][4];
#pragma unroll
  for (int m = 0; m < 8; ++m)
#pragma unroll
    for (int n = 0; n < 4; ++n) acc[m][n] = zv;
  bf16x8 af[4], bfr[4];

  PROLOGUE();
#pragma unroll 1
  for (int i = 0; i < NI - 1; ++i) {
    size_t kb = (size_t)i * 256;
    ITER_FULL(kb);
  }
  {
    size_t kb = (size_t)(NI - 1) * 256;
    ITER_LAST(kb);
  }

  // ---- epilogue: h1 (wc<2) -> LDS; h3 (wc>=2) computes g = silu(h1)*h3 ----
  float* hb = (float*)smem;                       // [256][130] f32
  if (wc < 2) {
#pragma unroll
    for (int m = 0; m < 8; ++m)
#pragma unroll
      for (int q = 0; q < 4; ++q) {
        int row = wr * 128 + m * 16 + (lane >> 4) * 4 + q;
        int col = wc * 64 + (lane & 15);
#pragma unroll
        for (int n = 0; n < 4; ++n)
          hb[row * 130 + col + n * 16] = acc[m][n][q];
      }
  }
  asm volatile("s_waitcnt lgkmcnt(0)" ::: "memory");
  wg_barrier();
  if (wc >= 2) {
#pragma unroll
    for (int m = 0; m < 8; ++m)
#pragma unroll
      for (int q = 0; q < 4; ++q) {
        int row = wr * 128 + m * 16 + (lane >> 4) * 4 + q;
        if (row >= rows) continue;
        size_t grow = (size_t)(mbase + row + gshift);
        int colbase = (wc - 2) * 64 + (lane & 15);
        unsigned short* gp = g + grow * HDIM + nt * 128 + colbase;
#pragma unroll
        for (int n = 0; n < 4; ++n) {
          float h1 = hb[row * 130 + colbase + n * 16];
          float h3 = acc[m][n][q];
          float gv = (h1 / (1.f + __expf(-h1))) * h3;
          gp[n * 16] = f2bf(gv);
        }
      }
  }
}

// =====================================================================
// GEMM2: out += wt * (g @ w2) via w2t, same schedule, atomic epilogue.
// =====================================================================
__global__ __launch_bounds__(512, 2) void gemm2_kernel(
    const unsigned short* __restrict__ g, const unsigned short* __restrict__ w2t,
    const int* __restrict__ tok_list, const float* __restrict__ tok_w,
    const int* __restrict__ counts, const int* __restrict__ offsets,
    float* __restrict__ out, int expert_fixed) {
  __shared__ __align__(16) char smem[131072];
  constexpr int NI = HDIM / 128;                // 56 iterations

  int nwg = gridDim.x;
  int orig = blockIdx.x;
  int wg = (orig & 7) * (nwg >> 3) + (orig >> 3);
  int mt = wg & (MT - 1);
  int rem = wg >> 5;
  int nt = rem % NT2;
  int e = expert_fixed >= 0 ? expert_fixed : rem / NT2;

  int cnt = counts[e];
  int mbase = mt * 256;
  if (mbase >= cnt) return;
  int off = offsets[e];
  int gshift = expert_fixed >= 0 ? 0 : off;
  int nbase = nt * 256;
  int rows = cnt - mbase; if (rows > 256) rows = 256;
  const unsigned short* w2te = w2t + (expert_fixed >= 0 ? (size_t)0 : (size_t)e * DDIM * HDIM);

  int tid = threadIdx.x, lane = tid & 63, wid = tid >> 6;
  int wr = wid >> 2, wc = wid & 3;

  int r16 = lane >> 2;
  int csrc = (lane & 3) ^ ((lane >> 3) & 3);
  const char* asrc[2]; const char* bsrc[2];
#pragma unroll
  for (int j = 0; j < 2; ++j) {
    int r = wid * 32 + j * 16 + r16;
    int m = mbase + r; if (m > cnt - 1) m = cnt - 1;
    asrc[j] = (const char*)g + (size_t)(m + gshift) * (HDIM * 2) + csrc * 16;
    bsrc[j] = (const char*)w2te + (size_t)(nbase + r) * (HDIM * 2) + csrc * 16;
  }
  int rA = (wr * 128 + (lane & 15)) * 64 + (((lane >> 4) ^ ((lane >> 1) & 3)) * 16);
  int rB = (wc * 64  + (lane & 15)) * 64 + (((lane >> 4) ^ ((lane >> 1) & 3)) * 16);

  f32x4 zv = {0.f, 0.f, 0.f, 0.f};
  f32x4 acc[8][4];
#pragma unroll
  for (int m = 0; m < 8; ++m)
#pragma unroll
    for (int n = 0; n < 4; ++n) acc[m][n] = zv;
  bf16x8 af[4], bfr[4];

  PROLOGUE();
#pragma unroll 1
  for (int i = 0; i < NI - 1; ++i) {
    size_t kb = (size_t)i * 256;
    ITER_FULL(kb);
  }
  {
    size_t kb = (size_t)(NI - 1) * 256;
    ITER_LAST(kb);
  }

#pragma unroll
  for (int m = 0; m < 8; ++m)
#pragma unroll
    for (int q = 0; q < 4; ++q) {
      int row = wr * 128 + m * 16 + (lane >> 4) * 4 + q;
      if (row >= rows) continue;
      int mi = mbase + row;
      int tok = tok_list[off + mi];
      float wt = tok_w[off + mi];
      float* op = out + (size_t)tok * DDIM + nbase + wc * 64 + (lane & 15);
#pragma unroll
      for (int n = 0; n < 4; ++n)
        atomicAdd(op + n * 16, acc[m][n][q] * wt);
    }
}

extern "C" void kernel_launch(void* const* d_in, const int* in_sizes, int n_in,
                              void* d_out, int out_size, void* d_ws, size_t ws_size,
                              hipStream_t stream) {
  const float* x      = (const float*)d_in[0];
  const float* gate_w = (const float*)d_in[1];
  const float* w1     = (const float*)d_in[2];
  const float* w2     = (const float*)d_in[3];
  const float* w3     = (const float*)d_in[4];
  float* out = (float*)d_out;
  char* ws = (char*)d_ws;

  size_t o = 0;
  int* counts  = (int*)(ws + o);
  int* offsets = counts + 8;
  int* cursor  = counts + 16;
  o += 256;
  int*   route_e = (int*)(ws + o);   o += (size_t)TT * 2 * 4;
  float* route_w = (float*)(ws + o); o += (size_t)TT * 2 * 4;
  int*   tok_list = (int*)(ws + o);  o += (size_t)TT * 2 * 4;
  float* tok_w = (float*)(ws + o);   o += (size_t)TT * 2 * 4;
  unsigned short* xbf = (unsigned short*)(ws + o); o += (size_t)TT * DDIM * 2;
  size_t fixed = o;

  const size_t WSZ = (size_t)HDIM * DDIM;
  const size_t wbf_full = (size_t)NEXP * WSZ * 2;
  const size_t gfull = (size_t)TT * 2 * HDIM * 2;

  hipMemsetAsync(counts, 0, 8 * sizeof(int), stream);
  hipMemsetAsync(out, 0, (size_t)TT * DDIM * sizeof(float), stream);
  cvt_bf16_kernel<<<4096, 256, 0, stream>>>(x, xbf, (long)TT * DDIM / 8);
  gate_kernel<<<TT, 256, 0, stream>>>(x, gate_w, route_e, route_w, counts);
  scan_kernel<<<1, 64, 0, stream>>>(counts, offsets, cursor);
  scatter_kernel<<<(TT + 255) / 256, 256, 0, stream>>>(route_e, route_w, cursor, tok_list, tok_w);

  if (ws_size >= fixed + 3 * wbf_full + gfull) {
    unsigned short* w1b = (unsigned short*)(ws + fixed);
    unsigned short* w3b = w1b + NEXP * WSZ;
    unsigned short* w2t = w3b + NEXP * WSZ;
    unsigned short* gbuf = w2t + NEXP * WSZ;
    cvt_bf16_kernel<<<8192, 256, 0, stream>>>(w1, w1b, (long)(NEXP * WSZ / 8));
    cvt_bf16_kernel<<<8192, 256, 0, stream>>>(w3, w3b, (long)(NEXP * WSZ / 8));
    transpose_w2_kernel<<<dim3(HDIM / 64, DDIM / 64, NEXP), 256, 0, stream>>>(w2, w2t, -1);
    gemm1_kernel<<<MT * NT1 * NEXP, 512, 0, stream>>>(
        xbf, w1b, w3b, tok_list, counts, offsets, gbuf, -1);
    gemm2_kernel<<<MT * NT2 * NEXP, 512, 0, stream>>>(
        gbuf, w2t, tok_list, tok_w, counts, offsets, out, -1);
  } else {
    unsigned short* w1b = (unsigned short*)(ws + fixed);
    unsigned short* w3b = w1b + WSZ;
    unsigned short* w2t = w3b + WSZ;
    unsigned short* gbuf = w2t + WSZ;
    for (int e = 0; e < NEXP; ++e) {
      cvt_bf16_kernel<<<4096, 256, 0, stream>>>(w1 + (size_t)e * WSZ, w1b, (long)(WSZ / 8));
      cvt_bf16_kernel<<<4096, 256, 0, stream>>>(w3 + (size_t)e * WSZ, w3b, (long)(WSZ / 8));
      transpose_w2_kernel<<<dim3(HDIM / 64, DDIM / 64, 1), 256, 0, stream>>>(w2, w2t, e);
      gemm1_kernel<<<MT * NT1, 512, 0, stream>>>(
          xbf, w1b, w3b, tok_list, counts, offsets, gbuf, e);
      gemm2_kernel<<<MT * NT2, 512, 0, stream>>>(
          gbuf, w2t, tok_list, tok_w, counts, offsets, out, e);
    }
  }
}